// Round 5
// baseline (142.449 us; speedup 1.0000x reference)
//
#include <hip/hip_runtime.h>
#include <hip/hip_bf16.h>

#define LOG2E 1.4426950408889634f
#define LN2   0.6931471805599453f

typedef __attribute__((ext_vector_type(8))) short bf16x8;
typedef __attribute__((ext_vector_type(4))) float f32x4;

static __device__ __forceinline__ short f2bf(float f) {
  __hip_bfloat16 h = __float2bfloat16(f);
  return *reinterpret_cast<short*>(&h);
}

static __device__ __forceinline__ void gll16(const float* gsrc, float* ldst) {
  // per-lane global src; LDS dest = wave-uniform base + lane*16B
  __builtin_amdgcn_global_load_lds(
      (const __attribute__((address_space(1))) void*)gsrc,
      (__attribute__((address_space(3))) void*)ldst, 16, 0, 0);
}

// ---------------------------------------------------------------------------
// wprep: pack W (f32 [256][64]) into per-lane MFMA B-fragments (bf16).
// wfrag[enc][f][lane][j], f=nsub*8+ks; elem = W[ks*32+(lane>>4)*8+j][nsub*16+(lane&15)]
// ---------------------------------------------------------------------------
__global__ __launch_bounds__(256) void wprep_kernel(
    const float* __restrict__ Ww, const float* __restrict__ Wi,
    ushort* __restrict__ wfrag)
{
  int id = blockIdx.x * 256 + threadIdx.x;       // 0..4095
  if (id >= 4096) return;
  int enc  = id >> 11;
  int f    = (id >> 6) & 31;
  int l    = id & 63;
  int nsub = f >> 3, ks = f & 7;
  const float* __restrict__ W = enc ? Wi : Ww;
  int n  = nsub * 16 + (l & 15);
  int k0 = ks * 32 + (l >> 4) * 8;
  ushort* dst = wfrag + ((size_t)(enc * 32 + f) * 64 + l) * 8;
#pragma unroll
  for (int j = 0; j < 8; ++j)
    dst[j] = (ushort)f2bf(W[(size_t)(k0 + j) * 64 + n]);
}

// ---------------------------------------------------------------------------
// enc_mfma4: block-cooperative strip pipeline.
// Block = 4 waves; per iteration the BLOCK does one 16-row strip: shared
// 16KB x tile (double-buffered), each wave stages 4 rows via global_load_lds
// and computes one 16-col output slice (nsub = wid). Counted vmcnt(8):
// strips i+1, i+2 loads stay in flight across barriers (never drained).
// LDS = 32KB W frags + 2*16KB x = 64KB -> 2 blocks/CU (8 waves).
// ---------------------------------------------------------------------------
__global__ __launch_bounds__(256, 2) void enc_mfma4_kernel(
    const float* __restrict__ x0, const float* __restrict__ b0,
    const float* __restrict__ x1, const float* __restrict__ b1,
    const ushort* __restrict__ wfrag, float* __restrict__ out, int M)
{
  __shared__ ushort sfrag[16384];                 // 32 KB W fragments
  __shared__ float  xbuf[2][4096];                // 2 x 16 KB shared x tiles

  const int enc = blockIdx.y;
  const float* __restrict__ x   = enc ? x1 : x0;
  const float* __restrict__ bia = enc ? b1 : b0;
  float* __restrict__ o = out + (size_t)enc * (size_t)M * 64u;

  const int lane = threadIdx.x & 63;
  const int wid  = threadIdx.x >> 6;
  const int rsel = lane & 15;                     // A row / C col within tile
  const int kgrp = lane >> 4;                     // k-group / C row-group
  const int sw   = rsel & 7;

  const int nstrips = (M + 15) >> 4;
  const int bx = blockIdx.x, G = gridDim.x;

  // cooperative LDS fill of W fragments (once)
  {
    const f32x4* src = (const f32x4*)wfrag + (size_t)enc * 2048;
    f32x4* dst = (f32x4*)sfrag;
#pragma unroll
    for (int i = 0; i < 8; ++i)
      dst[threadIdx.x + 256 * i] = src[threadIdx.x + 256 * i];
  }
  __syncthreads();

  const int niter = (bx < nstrips) ? ((nstrips - 1 - bx) / G + 1) : 0;
  if (niter == 0) return;                         // block-uniform

  const float bv = bia[wid * 16 + rsel];

  // wave stages its 4 rows of strip s into buffer `buf`
  auto stage = [&](int s, int buf) {
#pragma unroll
    for (int j = 0; j < 4; ++j) {
      int R = wid * 4 + j;
      int rg = s * 16 + R; if (rg >= M) rg = M - 1;
      const float* gs = x + (size_t)rg * 256u + ((lane ^ (R & 7)) << 2);
      gll16(gs, &xbuf[buf][R * 256]);
    }
  };

  // prologue: stage strips 0 and 1
  stage(bx, 0);
  if (niter > 1) {
    stage(bx + G, 1);
    asm volatile("s_waitcnt vmcnt(4)" ::: "memory");   // strip0 done
  } else {
    asm volatile("s_waitcnt vmcnt(0)" ::: "memory");
  }
  __builtin_amdgcn_sched_barrier(0);

  for (int i = 0; i < niter; ++i) {
    const int s = bx + i * G;
    if (i) {
      if (i == niter - 1) asm volatile("s_waitcnt vmcnt(4)" ::: "memory");
      else                asm volatile("s_waitcnt vmcnt(8)" ::: "memory");
      __builtin_amdgcn_sched_barrier(0);
    }
    __builtin_amdgcn_s_barrier();                 // strip-i tile visible to all
    __builtin_amdgcn_sched_barrier(0);

    const float* xb = xbuf[i & 1];

    // A-fragments: row rsel, chunks c0=ks*8+kgrp*2 (+1), XOR-swizzled
    bf16x8 a[8];
#pragma unroll
    for (int ks = 0; ks < 8; ++ks) {
      int c0 = ks * 8 + kgrp * 2;
      f32x4 lo = *(const f32x4*)&xb[rsel * 256 + (((c0    ) ^ sw) << 2)];
      f32x4 hi = *(const f32x4*)&xb[rsel * 256 + (((c0 + 1) ^ sw) << 2)];
      a[ks][0] = f2bf(lo.x); a[ks][1] = f2bf(lo.y);
      a[ks][2] = f2bf(lo.z); a[ks][3] = f2bf(lo.w);
      a[ks][4] = f2bf(hi.x); a[ks][5] = f2bf(hi.y);
      a[ks][6] = f2bf(hi.z); a[ks][7] = f2bf(hi.w);
    }

    asm volatile("s_waitcnt lgkmcnt(0)" ::: "memory");  // tile fully read
    __builtin_amdgcn_sched_barrier(0);
    __builtin_amdgcn_s_barrier();                 // ALL waves done reading
    __builtin_amdgcn_sched_barrier(0);

    // refill this buffer with strip i+2 (stays in flight through next strip)
    if (i + 2 < niter) stage(bx + (i + 2) * G, i & 1);

    // MFMA: this wave's 16-col slice (nsub = wid)
    f32x4 acc = f32x4{0.f, 0.f, 0.f, 0.f};
#pragma unroll
    for (int ks = 0; ks < 8; ++ks) {
      bf16x8 bfr = *(const bf16x8*)(sfrag + ((size_t)((wid * 8 + ks) * 64 + lane)) * 8);
      acc = __builtin_amdgcn_mfma_f32_16x16x32_bf16(a[ks], bfr, acc, 0, 0, 0);
    }

    // epilogue: bias + leaky relu; C/D: col=lane&15, row=kgrp*4+r
    const int crow = s * 16 + kgrp * 4;
#pragma unroll
    for (int r = 0; r < 4; ++r) {
      int rr = crow + r;
      if (rr < M) {
        float v = acc[r] + bv;
        v = fmaxf(v, 0.01f * v);
        o[(size_t)rr * 64u + wid * 16 + rsel] = v;
      }
    }
  }
}

// ---------------------------------------------------------------------------
// Kernel B: pw = xw @ W_edge[0:64,:] + b_edge ; pi = xi @ W_edge[64:128,:]
// rows padded to 16 floats (64B-aligned single-line gathers); b folded here.
// ---------------------------------------------------------------------------
__global__ __launch_bounds__(256) void proj_kernel(
    const float* __restrict__ feats, const float* __restrict__ W_edge,
    const float* __restrict__ b_edge, float* __restrict__ ws, int M)
{
  const int enc = blockIdx.y;
  int row = blockIdx.x * 256 + threadIdx.x;
  if (row >= M) return;
  const float4* __restrict__ f4 =
      (const float4*)(feats + ((size_t)enc * M + row) * 64u);
  const float* __restrict__ W2 = W_edge + enc * 640;   // 64 rows x 10 cols

  float acc[10];
#pragma unroll
  for (int k = 0; k < 10; ++k) acc[k] = enc ? 0.f : b_edge[k];

#pragma unroll 4
  for (int n4 = 0; n4 < 16; ++n4) {
    float4 xv = f4[n4];
    const float* w = W2 + n4 * 40;
#pragma unroll
    for (int k = 0; k < 10; ++k) acc[k] = fmaf(xv.x, w[k],      acc[k]);
#pragma unroll
    for (int k = 0; k < 10; ++k) acc[k] = fmaf(xv.y, w[10 + k], acc[k]);
#pragma unroll
    for (int k = 0; k < 10; ++k) acc[k] = fmaf(xv.z, w[20 + k], acc[k]);
#pragma unroll
    for (int k = 0; k < 10; ++k) acc[k] = fmaf(xv.w, w[30 + k], acc[k]);
  }

  float* orow = ws + ((size_t)enc * M + row) * 16u;
#pragma unroll
  for (int k = 0; k < 10; ++k) orow[k] = acc[k];
}

// ---------------------------------------------------------------------------
// Kernel C: logits[e] = pw[e0] + pi[e1] (bias pre-folded); log_softmax;
// dense float4 output stores via unpadded LDS transpose.
// ---------------------------------------------------------------------------
__global__ __launch_bounds__(256) void edge_kernel(
    const int* __restrict__ ei, const float* __restrict__ ws,
    float* __restrict__ out, int E, int M)
{
  __shared__ float sm[2560];
  long e = (long)blockIdx.x * 256 + threadIdx.x;
  float l[10];
#pragma unroll
  for (int k = 0; k < 10; ++k) l[k] = 0.f;

  if (e < E) {
    int e0 = ei[e];
    int e1 = ei[E + e];
    const float4* pw = (const float4*)ws + (size_t)e0 * 4u;
    const float4* pi = (const float4*)ws + ((size_t)M + e1) * 4u;
    float4 a0 = pw[0], a1 = pw[1], a2 = pw[2];
    float4 c0 = pi[0], c1 = pi[1], c2 = pi[2];
    l[0] = a0.x + c0.x; l[1] = a0.y + c0.y; l[2] = a0.z + c0.z; l[3] = a0.w + c0.w;
    l[4] = a1.x + c1.x; l[5] = a1.y + c1.y; l[6] = a1.z + c1.z; l[7] = a1.w + c1.w;
    l[8] = a2.x + c2.x; l[9] = a2.y + c2.y;
    float m = l[0];
#pragma unroll
    for (int k = 1; k < 10; ++k) m = fmaxf(m, l[k]);
    float s = 0.f;
#pragma unroll
    for (int k = 0; k < 10; ++k) { l[k] = (l[k] - m) * LOG2E; s += exp2f(l[k]); }
    float ls = log2f(s);
#pragma unroll
    for (int k = 0; k < 10; ++k) l[k] = (l[k] - ls) * LN2;
  }

#pragma unroll
  for (int k = 0; k < 10; ++k) sm[threadIdx.x * 10 + k] = l[k];
  __syncthreads();
  // 2560 floats = 640 float4, block-aligned dense stores
  const f32x4* sm4 = (const f32x4*)sm;
  f32x4* ob = (f32x4*)(out + (size_t)blockIdx.x * 2560u);
  long lim4 = ((long)E * 10) >> 2;                // E*10 divisible by 4
  long base4 = (long)blockIdx.x * 640;
#pragma unroll
  for (int j = 0; j < 3; ++j) {
    int idx = j * 256 + threadIdx.x;
    if (idx < 640 && base4 + idx < lim4) ob[idx] = sm4[idx];
  }
}

// ---------------------------------------------------------------------------
// Fallbacks (only if d_ws too small).
// ---------------------------------------------------------------------------
__global__ __launch_bounds__(256) void enc_kernel_f32(
    const float* __restrict__ x0, const float* __restrict__ W0, const float* __restrict__ b0,
    const float* __restrict__ x1, const float* __restrict__ W1, const float* __restrict__ b1,
    float* __restrict__ out, int M)
{
  const int enc = blockIdx.y;
  const float* __restrict__ x = enc ? x1 : x0;
  const float* __restrict__ W = enc ? W1 : W0;
  const float* __restrict__ b = enc ? b1 : b0;
  float* __restrict__ o = out + (size_t)enc * (size_t)M * 64u;

  const int lane = threadIdx.x & 63;
  const int wid  = threadIdx.x >> 6;
  int row0 = __builtin_amdgcn_readfirstlane(blockIdx.x * 64 + wid * 16);
  const float* __restrict__ xrow = x + (size_t)row0 * 256u;

  float acc[16];
#pragma unroll
  for (int r = 0; r < 16; ++r) acc[r] = 0.f;

  if (row0 + 16 <= M) {
#pragma unroll 4
    for (int k = 0; k < 256; ++k) {
      float wv = W[k * 64 + lane];
#pragma unroll
      for (int r = 0; r < 16; ++r)
        acc[r] = fmaf(xrow[r * 256 + k], wv, acc[r]);
    }
    float bias = b[lane];
#pragma unroll
    for (int r = 0; r < 16; ++r) {
      float v = acc[r] + bias;
      v = fmaxf(v, 0.01f * v);
      o[(size_t)(row0 + r) * 64u + lane] = v;
    }
  } else if (row0 < M) {
    int nr = M - row0;
    for (int k = 0; k < 256; ++k) {
      float wv = W[k * 64 + lane];
      for (int r = 0; r < nr; ++r)
        acc[r] = fmaf(xrow[r * 256 + k], wv, acc[r]);
    }
    float bias = b[lane];
    for (int r = 0; r < nr; ++r) {
      float v = acc[r] + bias;
      v = fmaxf(v, 0.01f * v);
      o[(size_t)(row0 + r) * 64u + lane] = v;
    }
  }
}

__global__ __launch_bounds__(256) void edge_kernel_direct(
    const int* __restrict__ ei, const float* __restrict__ feats,
    const float* __restrict__ W_edge, const float* __restrict__ b_edge,
    float* __restrict__ out, int E, int M)
{
  __shared__ float sm[2560];
  long e = (long)blockIdx.x * 256 + threadIdx.x;
  float l[10];
#pragma unroll
  for (int k = 0; k < 10; ++k) l[k] = 0.f;

  if (e < E) {
    int e0 = ei[e];
    int e1 = ei[E + e];
#pragma unroll
    for (int k = 0; k < 10; ++k) l[k] = b_edge[k];
    const float4* fw = (const float4*)(feats + (size_t)e0 * 64u);
    const float4* fi = (const float4*)(feats + ((size_t)M + e1) * 64u);
#pragma unroll 4
    for (int n4 = 0; n4 < 16; ++n4) {
      float4 xv = fw[n4];
      const float* w = W_edge + n4 * 40;
#pragma unroll
      for (int k = 0; k < 10; ++k) l[k] = fmaf(xv.x, w[k],      l[k]);
#pragma unroll
      for (int k = 0; k < 10; ++k) l[k] = fmaf(xv.y, w[10 + k], l[k]);
#pragma unroll
      for (int k = 0; k < 10; ++k) l[k] = fmaf(xv.z, w[20 + k], l[k]);
#pragma unroll
      for (int k = 0; k < 10; ++k) l[k] = fmaf(xv.w, w[30 + k], l[k]);
    }
#pragma unroll 4
    for (int n4 = 0; n4 < 16; ++n4) {
      float4 xv = fi[n4];
      const float* w = W_edge + 640 + n4 * 40;
#pragma unroll
      for (int k = 0; k < 10; ++k) l[k] = fmaf(xv.x, w[k],      l[k]);
#pragma unroll
      for (int k = 0; k < 10; ++k) l[k] = fmaf(xv.y, w[10 + k], l[k]);
#pragma unroll
      for (int k = 0; k < 10; ++k) l[k] = fmaf(xv.z, w[20 + k], l[k]);
#pragma unroll
      for (int k = 0; k < 10; ++k) l[k] = fmaf(xv.w, w[30 + k], l[k]);
    }
    float m = l[0];
#pragma unroll
    for (int k = 1; k < 10; ++k) m = fmaxf(m, l[k]);
    float s = 0.f;
#pragma unroll
    for (int k = 0; k < 10; ++k) { l[k] = (l[k] - m) * LOG2E; s += exp2f(l[k]); }
    float ls = log2f(s);
#pragma unroll
    for (int k = 0; k < 10; ++k) l[k] = (l[k] - ls) * LN2;
  }

#pragma unroll
  for (int k = 0; k < 10; ++k) sm[threadIdx.x * 10 + k] = l[k];
  __syncthreads();
  const f32x4* sm4 = (const f32x4*)sm;
  f32x4* ob = (f32x4*)(out + (size_t)blockIdx.x * 2560u);
  long lim4 = ((long)E * 10) >> 2;
  long base4 = (long)blockIdx.x * 640;
#pragma unroll
  for (int j = 0; j < 3; ++j) {
    int idx = j * 256 + threadIdx.x;
    if (idx < 640 && base4 + idx < lim4) ob[idx] = sm4[idx];
  }
}

extern "C" void kernel_launch(void* const* d_in, const int* in_sizes, int n_in,
                              void* d_out, int out_size, void* d_ws, size_t ws_size,
                              hipStream_t stream)
{
  const float* x_w = (const float*)d_in[0];
  const float* x_i = (const float*)d_in[1];
  const int*   ei  = (const int*)d_in[2];
  const float* W_w = (const float*)d_in[3];
  const float* b_w = (const float*)d_in[4];
  const float* W_i = (const float*)d_in[5];
  const float* b_i = (const float*)d_in[6];
  const float* W_e = (const float*)d_in[7];
  const float* b_e = (const float*)d_in[8];
  float* out = (float*)d_out;

  const int M = in_sizes[0] / 256;   // 100000
  const int E = in_sizes[2] / 2;     // 2000000

  float* logout = out + (size_t)2 * (size_t)M * 64u;

  const size_t pw_bytes = (size_t)2 * (size_t)M * 16u * sizeof(float);
  const size_t ws_need  = pw_bytes + 65536;     // + wfrag table

  if (ws_size >= ws_need) {
    float*  ws    = (float*)d_ws;
    ushort* wfrag = (ushort*)((char*)d_ws + pw_bytes);

    wprep_kernel<<<16, 256, 0, stream>>>(W_w, W_i, wfrag);

    dim3 gA(256, 2);                 // 512 blocks = 2/CU (LDS-limited)
    enc_mfma4_kernel<<<gA, 256, 0, stream>>>(x_w, b_w, x_i, b_i, wfrag, out, M);

    dim3 gB((M + 255) / 256, 2);
    proj_kernel<<<gB, 256, 0, stream>>>(out, W_e, b_e, ws, M);

    dim3 gC((unsigned)((E + 255) / 256));
    edge_kernel<<<gC, 256, 0, stream>>>(ei, ws, logout, E, M);
  } else {
    dim3 gA0((M + 63) / 64, 2);
    enc_kernel_f32<<<gA0, 256, 0, stream>>>(x_w, W_w, b_w, x_i, W_i, b_i, out, M);
    dim3 gC((unsigned)((E + 255) / 256));
    edge_kernel_direct<<<gC, 256, 0, stream>>>(ei, out, W_e, b_e, logout, E, M);
  }
}